// Round 7
// baseline (338.050 us; speedup 1.0000x reference)
//
#include <hip/hip_runtime.h>

// H2G2: 2-layer RGCN (R=4, per-relation mean) + mean-pool + linear.
// R10: register-resident fused layer (231us total, layer 47us). R11 FAILED:
//   launch_bounds(256,4) VGPR cap -> scratch spill (layer 221us). Never cap.
// R12 (229.6us): channel-split wave pair, merged one-hot loop, 8KB LDS
//   exchange: layer pinned at 47.0us == R10. FETCH 52MB = 8 XCD x 6.4MB full
//   per-XCD L2 replication (compulsory: random src gather).
// R13 FAILED: direct CSR place = random 4B global writes = line RMW.
// R14 FAILED: cooperative grid.sync ~80-90us each w/ mostly-idle grid.
// R15: CAP-bucket reservation WORKED; pool-fused layer2 FAILED (3.2M
//   device-scope atomics = 150us; XCD L2s non-coherent). No per-elem atomics.
// R16 (219.6us): memset(1KB) -> work(bin+weights+gstart+xconv) -> csr ->
//   layer1 -> layer2 -> pool. Layers 47.0 each.
// R17: WHY 47.0 is invariant: R10 = 12 waves/CU x 8 loads in flight = 96
//   lines/CU; R12/16 = 24 waves/CU x 4 = 96. Same MLP -> same time. At 900cy
//   HBM latency, 3 lines/cy/XCD needs ~84 lines/CU; we sit at 96 -> fill rate
//   0.9 lines/cy/XCD. FIX: unroll edge loop to 8 edges in flight (VGPR
//   ~100-110 -> 16 waves/CU x 8 = 128-160 lines/CU). Watch WRITE_SIZE for
//   spill (R11 mode); FETCH must stay ~52MB.

#define RR 4
#define HH 64
#define KK 320         // (RR+1)*HH
#define LWN (HH * KK)  // weights per layer = 20480
#define EPB 2048       // edges per bin chunk
#define CAP 6144       // per-bucket fixed capacity (mean 4096, +32 sigma)

using frag_ab = __attribute__((ext_vector_type(8))) short;
using frag_cd = __attribute__((ext_vector_type(4))) float;

__device__ inline short f2bf(float f) {
    unsigned u = __builtin_bit_cast(unsigned, f);
    unsigned r = u + 0x7fffu + ((u >> 16) & 1u);  // RNE
    return (short)(r >> 16);
}
__device__ inline float bf2f(short s) {
    unsigned u = ((unsigned)(unsigned short)s) << 16;
    return __builtin_bit_cast(float, u);
}

// ---- work: bin chunks | weights | gstart+sentinel | x conv (one dispatch) ----
__global__ __launch_bounds__(256) void work_kernel(
    const int* __restrict__ src, const int* __restrict__ dst,
    const int* __restrict__ et, int E,
    int* __restrict__ cur, int* __restrict__ tmp,
    const float* __restrict__ basis1, const float* __restrict__ comp1, const float* __restrict__ root1,
    const float* __restrict__ basis2, const float* __restrict__ comp2, const float* __restrict__ root2,
    short* __restrict__ W1t, short* __restrict__ W2t,
    const int* __restrict__ batch, int* __restrict__ gstart, int N, int G,
    int* __restrict__ rpflat,
    const float* __restrict__ x, short* __restrict__ Xb,
    int ebl, int wbl, int nb) {
    __shared__ int ss[256];
    __shared__ int lscan[257];
    __shared__ int lbase[256];
    __shared__ int lc2[256];
    __shared__ int sbuf[EPB];
    const int bid = blockIdx.x;
    const int t = threadIdx.x;

    if (bid < ebl) {  // ---- bin: LDS-staged bucket scatter into CAP regions ----
        const int e0 = bid * EPB;
        const int e1 = min(e0 + EPB, E);
        ss[t] = 0;
        __syncthreads();
        for (int e = e0 + t; e < e1; e += 256) atomicAdd(&ss[dst[e] >> 8], 1);
        __syncthreads();
        int v = ss[t];
        __syncthreads();
#pragma unroll
        for (int off = 1; off < 256; off <<= 1) {
            int u = (t >= off) ? ss[t - off] : 0;
            __syncthreads();
            ss[t] += u;
            __syncthreads();
        }
        lscan[t] = ss[t] - v;
        if (t == 255) lscan[256] = ss[255];
        lbase[t] = v ? t * CAP + atomicAdd(&cur[t], v) : 0;  // reserve
        lc2[t] = 0;
        __syncthreads();
        for (int e = e0 + t; e < e1; e += 256) {
            int d = dst[e];
            int b = d >> 8;
            int p = (src[e] << 10) | (et[e] << 8) | (d & 255);
            int pos = lscan[b] + atomicAdd(&lc2[b], 1);
            sbuf[pos] = p;
        }
        __syncthreads();
        int tot = lscan[256];
        for (int i = t; i < tot; i += 256) {
            int lo = 0, hi = 255;
            while (lo < hi) { int mid = (lo + hi + 1) >> 1; if (lscan[mid] <= i) lo = mid; else hi = mid - 1; }
            int idx = lbase[lo] + (i - lscan[lo]);
            if (idx - lo * CAP < CAP) tmp[idx] = sbuf[i];  // overflow shield
        }
    } else if (bid < ebl + wbl) {  // ---- weights: Wt[c*320+k] = Wstack[k][c] ----
        int w = (bid - ebl) * 256 + t;
        int layer = w / LWN;
        int rem = w - layer * LWN;
        int c = rem / KK;
        int k = rem - c * KK;
        const float* basis = layer ? basis2 : basis1;
        const float* comp  = layer ? comp2  : comp1;
        const float* root  = layer ? root2  : root1;
        short* Wt          = layer ? W2t    : W1t;
        float v;
        if (k < HH) {
            v = root[k * HH + c];
        } else {
            int r = (k >> 6) - 1, kk = k & 63;
            v = 0.f;
#pragma unroll
            for (int b = 0; b < RR; ++b) v += comp[r * RR + b] * basis[(b * HH + kk) * HH + c];
        }
        Wt[c * KK + k] = f2bf(v);
    } else if (bid < ebl + wbl + nb) {  // ---- gstart + rpflat sentinel ----
        int i = (bid - ebl - wbl) * 256 + t;
        if (i == 0) rpflat[4 * N] = E;
        if (i < N) {
            int b1 = batch[i];
            int b0 = (i == 0) ? -1 : batch[i - 1];
            for (int g = b0 + 1; g <= b1; ++g) gstart[g] = i;
            if (i == N - 1)
                for (int g = b1 + 1; g <= G; ++g) gstart[g] = N;
        }
    } else {  // ---- convert x fp32 -> bf16 ----
        int i4 = (bid - ebl - wbl - nb) * 256 + t;
        int base = i4 * 4;
        if (base < N * 64) {
            float4 f = *(const float4*)&x[base];
            short4 s;
            s.x = f2bf(f.x); s.y = f2bf(f.y); s.z = f2bf(f.z); s.w = f2bf(f.w);
            *(short4*)&Xb[base] = s;
        }
    }
}

// ---- csr: per-bucket (dl,rel) counting sort -> rpflat int4 + compact eidx ----
__global__ __launch_bounds__(256) void csr_kernel(const int* __restrict__ cur,
                                                  const int* __restrict__ tmp,
                                                  int* __restrict__ rpflat,
                                                  int* __restrict__ eidx, int N) {
    __shared__ int cnt4l[1024];
    __shared__ int ss[256];
    __shared__ int s0s, lens;
    const int b = blockIdx.x;
    const int t = threadIdx.x;
    // compact global start: scan bucket lengths
    int lv = min(cur[t], CAP);
    ss[t] = lv;
    __syncthreads();
#pragma unroll
    for (int off = 1; off < 256; off <<= 1) {
        int u = (t >= off) ? ss[t - off] : 0;
        __syncthreads();
        ss[t] += u;
        __syncthreads();
    }
    if (t == b) { s0s = ss[t] - lv; lens = lv; }
    __syncthreads();
    const int s0 = s0s, len = lens;
    const int tb = b * CAP;

    for (int i = t; i < 1024; i += 256) cnt4l[i] = 0;
    __syncthreads();
    for (int i = t; i < len; i += 256) {
        int e = tmp[tb + i];
        atomicAdd(&cnt4l[((e & 255) << 2) | ((e >> 8) & 3)], 1);
    }
    __syncthreads();
    int c0 = cnt4l[t * 4], c1 = cnt4l[t * 4 + 1], c2 = cnt4l[t * 4 + 2], c3 = cnt4l[t * 4 + 3];
    int deg = c0 + c1 + c2 + c3;
    ss[t] = deg;
    __syncthreads();
#pragma unroll
    for (int off = 1; off < 256; off <<= 1) {
        int u = (t >= off) ? ss[t - off] : 0;
        __syncthreads();
        ss[t] += u;
        __syncthreads();
    }
    int a0 = s0 + ss[t] - deg;
    int d = (b << 8) + t;
    if (d < N)
        *(int4*)&rpflat[d * 4] = make_int4(a0, a0 + c0, a0 + c0 + c1, a0 + c0 + c1 + c2);
    cnt4l[t * 4]     = a0;
    cnt4l[t * 4 + 1] = a0 + c0;
    cnt4l[t * 4 + 2] = a0 + c0 + c1;
    cnt4l[t * 4 + 3] = a0 + c0 + c1 + c2;
    __syncthreads();
    for (int i = t; i < len; i += 256) {
        int e = tmp[tb + i];
        int key = ((e & 255) << 2) | ((e >> 8) & 3);
        int pos = atomicAdd(&cnt4l[key], 1);
        eidx[pos] = ((e >> 10) << 2) | ((e >> 8) & 3);
    }
}

// ---- fused layer (R17): R12/R16 body with 8 edges in flight. ----
__global__ __launch_bounds__(256) void layer_kernel(
    const int* __restrict__ rpflat,
    const int* __restrict__ eidx,
    const short* __restrict__ Xb,
    const short* __restrict__ Wt,
    const float* __restrict__ bias,
    short* __restrict__ out, int n) {
    __shared__ short xpack[2][64][32];  // 8KB
    const int t = threadIdx.x;
    const int wv = t >> 6;
    const int pair = wv >> 1;   // which 16-node group
    const int ws = wv & 1;      // channel half: 0 = quad*8, 1 = 32+quad*8
    const int l = t & 63;
    const int m = l & 15;
    const int quad = l >> 4;
    const int node = blockIdx.x * 32 + pair * 16 + m;
    const bool valid = node < n;

    float acc[4][8];
#pragma unroll
    for (int r = 0; r < 4; ++r)
#pragma unroll
        for (int j = 0; j < 8; ++j) acc[r][j] = 0.f;

    int k0 = 0, k1 = 0;
    float4 iv = make_float4(0.f, 0.f, 0.f, 0.f);
    if (valid) {
        int4 r4 = *(const int4*)&rpflat[node * 4];
        int kend = rpflat[node * 4 + 4];
        k0 = r4.x;
        k1 = kend;
        iv.x = 1.0f / fmaxf((float)(r4.y - r4.x), 1.0f);
        iv.y = 1.0f / fmaxf((float)(r4.z - r4.y), 1.0f);
        iv.z = 1.0f / fmaxf((float)(r4.w - r4.z), 1.0f);
        iv.w = 1.0f / fmaxf((float)(kend - r4.w), 1.0f);
    }
    const short* xbq = Xb + ws * 32 + quad * 8;

#define ACC(P, F)                                                             \
    {                                                                         \
        int r_ = (P) & 3;                                                     \
        float s0_ = (r_ == 0) ? 1.f : 0.f;                                    \
        float s1_ = (r_ == 1) ? 1.f : 0.f;                                    \
        float s2_ = (r_ == 2) ? 1.f : 0.f;                                    \
        float s3_ = (r_ == 3) ? 1.f : 0.f;                                    \
        _Pragma("unroll") for (int j = 0; j < 8; ++j) {                       \
            float v_ = bf2f((F)[j]);                                          \
            acc[0][j] += v_ * s0_;                                            \
            acc[1][j] += v_ * s1_;                                            \
            acc[2][j] += v_ * s2_;                                            \
            acc[3][j] += v_ * s3_;                                            \
        }                                                                     \
    }

    int k = k0;
    for (; k + 7 < k1; k += 8) {  // 8 edges in flight (the MLP lever)
        int p0 = eidx[k];
        int p1 = eidx[k + 1];
        int p2 = eidx[k + 2];
        int p3 = eidx[k + 3];
        int p4 = eidx[k + 4];
        int p5 = eidx[k + 5];
        int p6 = eidx[k + 6];
        int p7 = eidx[k + 7];
        const short* a0p = xbq + (size_t)(p0 >> 2) * 64;
        const short* a1p = xbq + (size_t)(p1 >> 2) * 64;
        const short* a2p = xbq + (size_t)(p2 >> 2) * 64;
        const short* a3p = xbq + (size_t)(p3 >> 2) * 64;
        const short* a4p = xbq + (size_t)(p4 >> 2) * 64;
        const short* a5p = xbq + (size_t)(p5 >> 2) * 64;
        const short* a6p = xbq + (size_t)(p6 >> 2) * 64;
        const short* a7p = xbq + (size_t)(p7 >> 2) * 64;
        frag_ab f0 = *(const frag_ab*)a0p;
        frag_ab f1 = *(const frag_ab*)a1p;
        frag_ab f2 = *(const frag_ab*)a2p;
        frag_ab f3 = *(const frag_ab*)a3p;
        frag_ab f4 = *(const frag_ab*)a4p;
        frag_ab f5 = *(const frag_ab*)a5p;
        frag_ab f6 = *(const frag_ab*)a6p;
        frag_ab f7 = *(const frag_ab*)a7p;
        ACC(p0, f0)
        ACC(p1, f1)
        ACC(p2, f2)
        ACC(p3, f3)
        ACC(p4, f4)
        ACC(p5, f5)
        ACC(p6, f6)
        ACC(p7, f7)
    }
    if (k + 3 < k1) {  // 4-wide mid step
        int p0 = eidx[k];
        int p1 = eidx[k + 1];
        int p2 = eidx[k + 2];
        int p3 = eidx[k + 3];
        k += 4;
        const short* a0p = xbq + (size_t)(p0 >> 2) * 64;
        const short* a1p = xbq + (size_t)(p1 >> 2) * 64;
        const short* a2p = xbq + (size_t)(p2 >> 2) * 64;
        const short* a3p = xbq + (size_t)(p3 >> 2) * 64;
        frag_ab f0 = *(const frag_ab*)a0p;
        frag_ab f1 = *(const frag_ab*)a1p;
        frag_ab f2 = *(const frag_ab*)a2p;
        frag_ab f3 = *(const frag_ab*)a3p;
        ACC(p0, f0)
        ACC(p1, f1)
        ACC(p2, f2)
        ACC(p3, f3)
    }
    for (; k < k1; ++k) {
        int p0 = eidx[k];
        const short* a0p = xbq + (size_t)(p0 >> 2) * 64;
        frag_ab f0 = *(const frag_ab*)a0p;
        ACC(p0, f0)
    }
#undef ACC

    frag_ab y[4];
    {
        float s0 = iv.x, s1 = iv.y, s2 = iv.z, s3 = iv.w;
#pragma unroll
        for (int j = 0; j < 8; ++j) {
            y[0][j] = f2bf(acc[0][j] * s0);
            y[1][j] = f2bf(acc[1][j] * s1);
            y[2][j] = f2bf(acc[2][j] * s2);
            y[3][j] = f2bf(acc[3][j] * s3);
        }
    }

    if (ws == 1) {
#pragma unroll
        for (int r = 0; r < 4; ++r)
            *(frag_ab*)&xpack[pair][l][r * 8] = y[r];
    }
    __syncthreads();
    if (ws == 1) return;

    frag_ab a[10];
    a[0] = frag_ab{};
    a[1] = frag_ab{};
    if (valid) {
        const short* xr = Xb + (size_t)node * 64 + quad * 8;
        a[0] = *(const frag_ab*)xr;
        a[1] = *(const frag_ab*)(xr + 32);
    }
#pragma unroll
    for (int r = 0; r < 4; ++r) {
        a[2 + 2 * r] = y[r];
        a[3 + 2 * r] = *(const frag_ab*)&xpack[pair][l][r * 8];
    }

    const int nrow_base = blockIdx.x * 32 + pair * 16 + quad * 4;
#pragma unroll
    for (int ct = 0; ct < 4; ++ct) {
        const short* bp = Wt + (size_t)(ct * 16 + m) * KK + quad * 8;
        frag_cd c = {0.f, 0.f, 0.f, 0.f};
#pragma unroll
        for (int f = 0; f < 10; ++f) {
            frag_ab bf = *(const frag_ab*)(bp + f * 32);
            c = __builtin_amdgcn_mfma_f32_16x16x32_bf16(a[f], bf, c, 0, 0, 0);
        }
        int col = ct * 16 + m;
        float bv = bias[col];
#pragma unroll
        for (int r = 0; r < 4; ++r) {
            int nr = nrow_base + r;
            if (nr < n) out[(size_t)nr * 64 + col] = f2bf(fmaxf(c[r] + bv, 0.f));
        }
    }
}

// ---- pool (segmented) + classifier ----
__global__ __launch_bounds__(256) void pool_cls_kernel(const short* __restrict__ h2,
                                                       const int* __restrict__ gstart,
                                                       const float* __restrict__ w,
                                                       const float* __restrict__ b,
                                                       float* __restrict__ out) {
    __shared__ float red[4][64];
    const int g = blockIdx.x;
    const int t = threadIdx.x;
    const int h = t & 63;
    const int wv = t >> 6;
    const int s = gstart[g], e = gstart[g + 1];

    float acc = 0.f;
    for (int i = s + wv; i < e; i += 4) acc += bf2f(h2[(size_t)i * 64 + h]);
    red[wv][h] = acc;
    __syncthreads();
    if (wv == 0) {
        float sum = red[0][h] + red[1][h] + red[2][h] + red[3][h];
        red[0][h] = sum / fmaxf((float)(e - s), 1.0f);
    }
    __syncthreads();
    if (t < 4) {
        float sres = 0.f;
#pragma unroll 8
        for (int hh = 0; hh < 64; ++hh) sres += red[0][hh] * w[hh * 4 + t];
        out[g * 4 + t] = sres + b[t];
    }
}

extern "C" void kernel_launch(void* const* d_in, const int* in_sizes, int n_in,
                              void* d_out, int out_size, void* d_ws, size_t ws_size,
                              hipStream_t stream) {
    const float* x        = (const float*)d_in[0];
    const int* edge_index = (const int*)d_in[1];
    const int* edge_type  = (const int*)d_in[2];
    const int* batch      = (const int*)d_in[3];
    const float* basis1 = (const float*)d_in[4];
    const float* comp1  = (const float*)d_in[5];
    const float* root1  = (const float*)d_in[6];
    const float* bias1  = (const float*)d_in[7];
    const float* basis2 = (const float*)d_in[8];
    const float* comp2  = (const float*)d_in[9];
    const float* root2  = (const float*)d_in[10];
    const float* bias2  = (const float*)d_in[11];
    const float* clas_w = (const float*)d_in[12];
    const float* clas_b = (const float*)d_in[13];

    const int N = in_sizes[0] / 64;
    const int E = in_sizes[2];
    const int G = out_size / 4;
    const int* src = edge_index;
    const int* dst = edge_index + E;
    const int nbuck = (N + 255) >> 8;

    char* base = (char*)d_ws;
    size_t off = 0;
    auto carve = [&](size_t bytes) { void* p = base + off; off = (off + bytes + 15) & ~(size_t)15; return p; };
    int*   cur     = (int*)carve(sizeof(int) * 256);
    int*   rpflat  = (int*)carve(sizeof(int) * ((size_t)N * 4 + 4));
    int*   gstart  = (int*)carve(sizeof(int) * ((size_t)G + 1));
    int*   eidx    = (int*)carve(sizeof(int) * (size_t)E);
    int*   tmp     = (int*)carve(sizeof(int) * (size_t)nbuck * CAP);
    short* W1t     = (short*)carve(sizeof(short) * LWN);
    short* W2t     = (short*)carve(sizeof(short) * LWN);
    short* Xb1     = (short*)carve(sizeof(short) * (size_t)N * 64);
    short* H1      = (short*)carve(sizeof(short) * (size_t)N * 64);
    short* H2      = (short*)carve(sizeof(short) * (size_t)N * 64);
    float* gout    = (float*)d_out;

    const int ebl = (E + EPB - 1) / EPB;
    const int wbl = (2 * LWN + 255) / 256;
    const int nb  = (N + 255) / 256;
    const int cvb = (N * 64 / 4 + 255) / 256;
    const int work_blocks = ebl + wbl + nb + cvb;
    const int layer_blocks = (N + 31) / 32;

    hipMemsetAsync(cur, 0, sizeof(int) * 256, stream);

    work_kernel<<<work_blocks, 256, 0, stream>>>(
        src, dst, edge_type, E, cur, tmp,
        basis1, comp1, root1, basis2, comp2, root2, W1t, W2t,
        batch, gstart, N, G, rpflat, x, Xb1, ebl, wbl, nb);
    csr_kernel<<<nbuck, 256, 0, stream>>>(cur, tmp, rpflat, eidx, N);

    layer_kernel<<<layer_blocks, 256, 0, stream>>>(rpflat, eidx, Xb1, W1t, bias1, H1, N);
    layer_kernel<<<layer_blocks, 256, 0, stream>>>(rpflat, eidx, H1, W2t, bias2, H2, N);

    pool_cls_kernel<<<G, 256, 0, stream>>>(H2, gstart, clas_w, clas_b, gout);
}

// Round 8
// 275.000 us; speedup vs baseline: 1.2293x; 1.2293x over previous
//
#include <hip/hip_runtime.h>

// H2G2: 2-layer RGCN (R=4, per-relation mean) + mean-pool + linear.
// R10 (231us, layer 47): register-resident fused layer. R11 FAILED: VGPR cap
//   -> scratch spill. Never cap min-waves.
// R12 (229.6): channel-split wave pair; layer pinned at 47.0 == R10.
// R13 FAILED: random 4B global writes = line RMW. R14 FAILED: grid.sync
//   ~80-90us each w/ mostly-idle grid. R15: CAP-bucket OK; pool-fusion FAILED
//   via 3.2M per-ELEMENT device atomics (=150us). R16 (219.6, BEST): memset ->
//   work -> csr -> layer1 -> layer2 -> pool.
// R17 FAILED (338): 8-edge unroll -> VGPR 140 -> occ 27.6->7.9% -> lines
//   in flight DOWN -> layer 107us. CONFIRMS MLP model: time ~ 1/(waves x
//   depth), saturating at the per-XCD L2 MSHR ceiling (~1.9k lines/XCD via
//   Little: 1.09TB/s x 900ns). FETCH 51.8MB = 8 XCD x 6.4MB = compulsory
//   floor (perfect per-XCD reuse). Layer gather = HW roofline ~47us. FROZEN.
// R18: attack non-layer 125us. (a) pool+cls fused into layer2 the RIGHT way:
//   LDS-first reduction (pgs[8][64] per block; 32 batch-sorted nodes span
//   ~1-2 graphs) -> ~128 device atomics/block (~200k total, 16x less than
//   R15) -> done-counter elects last block for the 131K-MAC classifier.
//   Deletes pool dispatch + H2 12.8MB round-trip. (b) csr 512 threads (was
//   196 blocks x 256 = 0.77 blk/CU). Pipeline: memset -> work -> csr ->
//   layer1 -> layer2(+pool+cls) = 4 kernels + memset.

#define RR 4
#define HH 64
#define KK 320         // (RR+1)*HH
#define LWN (HH * KK)  // weights per layer = 20480
#define EPB 2048       // edges per bin chunk
#define CAP 6144       // per-bucket fixed capacity (mean 4096, +32 sigma)
#define NSLOT 8        // LDS pool slots (block spans <=2 graphs w.h.p.)

using frag_ab = __attribute__((ext_vector_type(8))) short;
using frag_cd = __attribute__((ext_vector_type(4))) float;

__device__ inline short f2bf(float f) {
    unsigned u = __builtin_bit_cast(unsigned, f);
    unsigned r = u + 0x7fffu + ((u >> 16) & 1u);  // RNE
    return (short)(r >> 16);
}
__device__ inline float bf2f(short s) {
    unsigned u = ((unsigned)(unsigned short)s) << 16;
    return __builtin_bit_cast(float, u);
}

// ---- work: bin chunks | weights | gstart+sentinel | x conv (one dispatch) ----
__global__ __launch_bounds__(256) void work_kernel(
    const int* __restrict__ src, const int* __restrict__ dst,
    const int* __restrict__ et, int E,
    int* __restrict__ cur, int* __restrict__ tmp,
    const float* __restrict__ basis1, const float* __restrict__ comp1, const float* __restrict__ root1,
    const float* __restrict__ basis2, const float* __restrict__ comp2, const float* __restrict__ root2,
    short* __restrict__ W1t, short* __restrict__ W2t,
    const int* __restrict__ batch, int* __restrict__ gstart, int N, int G,
    int* __restrict__ rpflat,
    const float* __restrict__ x, short* __restrict__ Xb,
    int ebl, int wbl, int nb) {
    __shared__ int ss[256];
    __shared__ int lscan[257];
    __shared__ int lbase[256];
    __shared__ int lc2[256];
    __shared__ int sbuf[EPB];
    const int bid = blockIdx.x;
    const int t = threadIdx.x;

    if (bid < ebl) {  // ---- bin: LDS-staged bucket scatter into CAP regions ----
        const int e0 = bid * EPB;
        const int e1 = min(e0 + EPB, E);
        ss[t] = 0;
        __syncthreads();
        for (int e = e0 + t; e < e1; e += 256) atomicAdd(&ss[dst[e] >> 8], 1);
        __syncthreads();
        int v = ss[t];
        __syncthreads();
#pragma unroll
        for (int off = 1; off < 256; off <<= 1) {
            int u = (t >= off) ? ss[t - off] : 0;
            __syncthreads();
            ss[t] += u;
            __syncthreads();
        }
        lscan[t] = ss[t] - v;
        if (t == 255) lscan[256] = ss[255];
        lbase[t] = v ? t * CAP + atomicAdd(&cur[t], v) : 0;  // reserve
        lc2[t] = 0;
        __syncthreads();
        for (int e = e0 + t; e < e1; e += 256) {
            int d = dst[e];
            int b = d >> 8;
            int p = (src[e] << 10) | (et[e] << 8) | (d & 255);
            int pos = lscan[b] + atomicAdd(&lc2[b], 1);
            sbuf[pos] = p;
        }
        __syncthreads();
        int tot = lscan[256];
        for (int i = t; i < tot; i += 256) {
            int lo = 0, hi = 255;
            while (lo < hi) { int mid = (lo + hi + 1) >> 1; if (lscan[mid] <= i) lo = mid; else hi = mid - 1; }
            int idx = lbase[lo] + (i - lscan[lo]);
            if (idx - lo * CAP < CAP) tmp[idx] = sbuf[i];  // overflow shield
        }
    } else if (bid < ebl + wbl) {  // ---- weights: Wt[c*320+k] = Wstack[k][c] ----
        int w = (bid - ebl) * 256 + t;
        int layer = w / LWN;
        int rem = w - layer * LWN;
        int c = rem / KK;
        int k = rem - c * KK;
        const float* basis = layer ? basis2 : basis1;
        const float* comp  = layer ? comp2  : comp1;
        const float* root  = layer ? root2  : root1;
        short* Wt          = layer ? W2t    : W1t;
        float v;
        if (k < HH) {
            v = root[k * HH + c];
        } else {
            int r = (k >> 6) - 1, kk = k & 63;
            v = 0.f;
#pragma unroll
            for (int b = 0; b < RR; ++b) v += comp[r * RR + b] * basis[(b * HH + kk) * HH + c];
        }
        Wt[c * KK + k] = f2bf(v);
    } else if (bid < ebl + wbl + nb) {  // ---- gstart + rpflat sentinel ----
        int i = (bid - ebl - wbl) * 256 + t;
        if (i == 0) rpflat[4 * N] = E;
        if (i < N) {
            int b1 = batch[i];
            int b0 = (i == 0) ? -1 : batch[i - 1];
            for (int g = b0 + 1; g <= b1; ++g) gstart[g] = i;
            if (i == N - 1)
                for (int g = b1 + 1; g <= G; ++g) gstart[g] = N;
        }
    } else {  // ---- convert x fp32 -> bf16 ----
        int i4 = (bid - ebl - wbl - nb) * 256 + t;
        int base = i4 * 4;
        if (base < N * 64) {
            float4 f = *(const float4*)&x[base];
            short4 s;
            s.x = f2bf(f.x); s.y = f2bf(f.y); s.z = f2bf(f.z); s.w = f2bf(f.w);
            *(short4*)&Xb[base] = s;
        }
    }
}

// ---- csr (512 thr): per-bucket (dl,rel) counting sort -> rpflat + eidx ----
__global__ __launch_bounds__(512) void csr_kernel(const int* __restrict__ cur,
                                                  const int* __restrict__ tmp,
                                                  int* __restrict__ rpflat,
                                                  int* __restrict__ eidx, int N) {
    __shared__ int cnt4l[1024];
    __shared__ int ss[256];
    __shared__ int s0s, lens;
    const int b = blockIdx.x;
    const int t = threadIdx.x;
    // compact global start: scan bucket lengths (threads t<256 active)
    int lv = 0;
    if (t < 256) { lv = min(cur[t], CAP); ss[t] = lv; }
    __syncthreads();
#pragma unroll
    for (int off = 1; off < 256; off <<= 1) {
        int u = (t >= off && t < 256) ? ss[t - off] : 0;
        __syncthreads();
        if (t < 256) ss[t] += u;
        __syncthreads();
    }
    if (t == b) { s0s = ss[t] - lv; lens = lv; }
    __syncthreads();
    const int s0 = s0s, len = lens;
    const int tb = b * CAP;

    for (int i = t; i < 1024; i += 512) cnt4l[i] = 0;
    __syncthreads();
    for (int i = t; i < len; i += 512) {
        int e = tmp[tb + i];
        atomicAdd(&cnt4l[((e & 255) << 2) | ((e >> 8) & 3)], 1);
    }
    __syncthreads();
    int c0 = 0, c1 = 0, c2 = 0, c3 = 0, deg = 0;
    if (t < 256) {
        c0 = cnt4l[t * 4]; c1 = cnt4l[t * 4 + 1];
        c2 = cnt4l[t * 4 + 2]; c3 = cnt4l[t * 4 + 3];
        deg = c0 + c1 + c2 + c3;
        ss[t] = deg;
    }
    __syncthreads();
#pragma unroll
    for (int off = 1; off < 256; off <<= 1) {
        int u = (t >= off && t < 256) ? ss[t - off] : 0;
        __syncthreads();
        if (t < 256) ss[t] += u;
        __syncthreads();
    }
    if (t < 256) {
        int a0 = s0 + ss[t] - deg;
        int d = (b << 8) + t;
        if (d < N)
            *(int4*)&rpflat[d * 4] = make_int4(a0, a0 + c0, a0 + c0 + c1, a0 + c0 + c1 + c2);
        cnt4l[t * 4]     = a0;
        cnt4l[t * 4 + 1] = a0 + c0;
        cnt4l[t * 4 + 2] = a0 + c0 + c1;
        cnt4l[t * 4 + 3] = a0 + c0 + c1 + c2;
    }
    __syncthreads();
    for (int i = t; i < len; i += 512) {
        int e = tmp[tb + i];
        int key = ((e & 255) << 2) | ((e >> 8) & 3);
        int pos = atomicAdd(&cnt4l[key], 1);
        eidx[pos] = ((e >> 10) << 2) | ((e >> 8) & 3);
    }
}

// ---- fused layer (R16 body, FROZEN gather). do_pool: LDS-first pooling +
//      elected-last-block classifier; no H2. ----
__global__ __launch_bounds__(256) void layer_kernel(
    const int* __restrict__ rpflat,
    const int* __restrict__ eidx,
    const short* __restrict__ Xb,
    const short* __restrict__ Wt,
    const float* __restrict__ bias,
    short* __restrict__ out, int n, int do_pool,
    const int* __restrict__ batch, float* __restrict__ gsum,
    int* __restrict__ done, const int* __restrict__ gstart, int G,
    const float* __restrict__ clas_w, const float* __restrict__ clas_b,
    float* __restrict__ gout) {
    __shared__ short xpack[2][64][32];  // 8KB
    __shared__ float pgs[NSLOT * 64];   // 2KB pooled partials
    __shared__ int winner;
    const int t = threadIdx.x;
    const int wv = t >> 6;
    const int pair = wv >> 1;   // which 16-node group
    const int ws = wv & 1;      // channel half: 0 = quad*8, 1 = 32+quad*8
    const int l = t & 63;
    const int m = l & 15;
    const int quad = l >> 4;
    const int node = blockIdx.x * 32 + pair * 16 + m;
    const bool valid = node < n;

    float acc[4][8];
#pragma unroll
    for (int r = 0; r < 4; ++r)
#pragma unroll
        for (int j = 0; j < 8; ++j) acc[r][j] = 0.f;

    int k0 = 0, k1 = 0;
    float4 iv = make_float4(0.f, 0.f, 0.f, 0.f);
    if (valid) {
        int4 r4 = *(const int4*)&rpflat[node * 4];
        int kend = rpflat[node * 4 + 4];
        k0 = r4.x;
        k1 = kend;
        iv.x = 1.0f / fmaxf((float)(r4.y - r4.x), 1.0f);
        iv.y = 1.0f / fmaxf((float)(r4.z - r4.y), 1.0f);
        iv.z = 1.0f / fmaxf((float)(r4.w - r4.z), 1.0f);
        iv.w = 1.0f / fmaxf((float)(kend - r4.w), 1.0f);
    }
    const short* xbq = Xb + ws * 32 + quad * 8;

#define ACC(P, F)                                                             \
    {                                                                         \
        int r_ = (P) & 3;                                                     \
        float s0_ = (r_ == 0) ? 1.f : 0.f;                                    \
        float s1_ = (r_ == 1) ? 1.f : 0.f;                                    \
        float s2_ = (r_ == 2) ? 1.f : 0.f;                                    \
        float s3_ = (r_ == 3) ? 1.f : 0.f;                                    \
        _Pragma("unroll") for (int j = 0; j < 8; ++j) {                       \
            float v_ = bf2f((F)[j]);                                          \
            acc[0][j] += v_ * s0_;                                            \
            acc[1][j] += v_ * s1_;                                            \
            acc[2][j] += v_ * s2_;                                            \
            acc[3][j] += v_ * s3_;                                            \
        }                                                                     \
    }

    int k = k0;
    for (; k + 3 < k1; k += 4) {  // 4 edges in flight (FROZEN: MSHR-optimal)
        int p0 = eidx[k];
        int p1 = eidx[k + 1];
        int p2 = eidx[k + 2];
        int p3 = eidx[k + 3];
        const short* a0p = xbq + (size_t)(p0 >> 2) * 64;
        const short* a1p = xbq + (size_t)(p1 >> 2) * 64;
        const short* a2p = xbq + (size_t)(p2 >> 2) * 64;
        const short* a3p = xbq + (size_t)(p3 >> 2) * 64;
        frag_ab f0 = *(const frag_ab*)a0p;
        frag_ab f1 = *(const frag_ab*)a1p;
        frag_ab f2 = *(const frag_ab*)a2p;
        frag_ab f3 = *(const frag_ab*)a3p;
        ACC(p0, f0)
        ACC(p1, f1)
        ACC(p2, f2)
        ACC(p3, f3)
    }
    for (; k < k1; ++k) {
        int p0 = eidx[k];
        const short* a0p = xbq + (size_t)(p0 >> 2) * 64;
        frag_ab f0 = *(const frag_ab*)a0p;
        ACC(p0, f0)
    }
#undef ACC

    frag_ab y[4];
    {
        float s0 = iv.x, s1 = iv.y, s2 = iv.z, s3 = iv.w;
#pragma unroll
        for (int j = 0; j < 8; ++j) {
            y[0][j] = f2bf(acc[0][j] * s0);
            y[1][j] = f2bf(acc[1][j] * s1);
            y[2][j] = f2bf(acc[2][j] * s2);
            y[3][j] = f2bf(acc[3][j] * s3);
        }
    }

    if (ws == 1) {
#pragma unroll
        for (int r = 0; r < 4; ++r)
            *(frag_ab*)&xpack[pair][l][r * 8] = y[r];
        if (do_pool) {  // ws=1 waves zero the pool partials (idle otherwise)
            int local = pair * 64 + l;  // 0..127
            for (int i = local; i < NSLOT * 64; i += 128) pgs[i] = 0.f;
        }
    }
    __syncthreads();
    if (!do_pool && ws == 1) return;

    const int nrow_base = blockIdx.x * 32 + pair * 16 + quad * 4;
    const int batch_base = do_pool ? batch[blockIdx.x * 32] : 0;

    if (ws == 0) {
        frag_ab a[10];
        a[0] = frag_ab{};
        a[1] = frag_ab{};
        if (valid) {
            const short* xr = Xb + (size_t)node * 64 + quad * 8;
            a[0] = *(const frag_ab*)xr;
            a[1] = *(const frag_ab*)(xr + 32);
        }
#pragma unroll
        for (int r = 0; r < 4; ++r) {
            a[2 + 2 * r] = y[r];
            a[3 + 2 * r] = *(const frag_ab*)&xpack[pair][l][r * 8];
        }

        int bv4[4];
        if (do_pool) {
            if (nrow_base + 3 < n) {
                int4 bb = *(const int4*)&batch[nrow_base];
                bv4[0] = bb.x; bv4[1] = bb.y; bv4[2] = bb.z; bv4[3] = bb.w;
            } else {
#pragma unroll
                for (int r = 0; r < 4; ++r)
                    bv4[r] = (nrow_base + r < n) ? batch[nrow_base + r] : 0;
            }
        }

#pragma unroll
        for (int ct = 0; ct < 4; ++ct) {
            const short* bp = Wt + (size_t)(ct * 16 + m) * KK + quad * 8;
            frag_cd c = {0.f, 0.f, 0.f, 0.f};
#pragma unroll
            for (int f = 0; f < 10; ++f) {
                frag_ab bf = *(const frag_ab*)(bp + f * 32);
                c = __builtin_amdgcn_mfma_f32_16x16x32_bf16(a[f], bf, c, 0, 0, 0);
            }
            int col = ct * 16 + m;
            float bv = bias[col];
            if (do_pool) {
#pragma unroll
                for (int r = 0; r < 4; ++r) {
                    int nr = nrow_base + r;
                    if (nr < n) {
                        float v = fmaxf(c[r] + bv, 0.f);
                        int g = bv4[r] - batch_base;
                        if (g < NSLOT)
                            atomicAdd(&pgs[g * 64 + col], v);
                        else
                            atomicAdd(&gsum[(size_t)bv4[r] * 64 + col], v);
                    }
                }
            } else {
#pragma unroll
                for (int r = 0; r < 4; ++r) {
                    int nr = nrow_base + r;
                    if (nr < n) out[(size_t)nr * 64 + col] = f2bf(fmaxf(c[r] + bv, 0.f));
                }
            }
        }
    }

    if (do_pool) {
        __syncthreads();
        // flush block partials: ~ (gspan+1)*64 device-scope atomics
        int node_last = min(blockIdx.x * 32 + 31, n - 1);
        int gspan = batch[node_last] - batch_base;
        for (int i = t; i < NSLOT * 64; i += 256) {
            int s = i >> 6;
            if (s <= gspan) {
                float v = pgs[i];
                if (v != 0.f) atomicAdd(&gsum[(size_t)(batch_base + s) * 64 + (i & 63)], v);
            }
        }
        // elect last block to classify
        if (t == 0) {
            __threadfence();
            int old = __hip_atomic_fetch_add(done, 1, __ATOMIC_ACQ_REL,
                                             __HIP_MEMORY_SCOPE_AGENT);
            winner = (old == (int)gridDim.x - 1) ? 1 : 0;
        }
        __syncthreads();
        if (winner) {
            for (int g = t; g < G; g += 256) {
                int s = gstart[g], e = gstart[g + 1];
                float invc = 1.0f / fmaxf((float)(e - s), 1.0f);
                float o0 = 0.f, o1 = 0.f, o2 = 0.f, o3 = 0.f;
                for (int hh = 0; hh < 64; ++hh) {
                    float hv = __hip_atomic_load(&gsum[(size_t)g * 64 + hh],
                                                 __ATOMIC_RELAXED,
                                                 __HIP_MEMORY_SCOPE_AGENT);
                    float mm = hv * invc;
                    o0 += mm * clas_w[hh * 4 + 0];
                    o1 += mm * clas_w[hh * 4 + 1];
                    o2 += mm * clas_w[hh * 4 + 2];
                    o3 += mm * clas_w[hh * 4 + 3];
                }
                gout[g * 4 + 0] = o0 + clas_b[0];
                gout[g * 4 + 1] = o1 + clas_b[1];
                gout[g * 4 + 2] = o2 + clas_b[2];
                gout[g * 4 + 3] = o3 + clas_b[3];
            }
        }
    }
}

extern "C" void kernel_launch(void* const* d_in, const int* in_sizes, int n_in,
                              void* d_out, int out_size, void* d_ws, size_t ws_size,
                              hipStream_t stream) {
    const float* x        = (const float*)d_in[0];
    const int* edge_index = (const int*)d_in[1];
    const int* edge_type  = (const int*)d_in[2];
    const int* batch      = (const int*)d_in[3];
    const float* basis1 = (const float*)d_in[4];
    const float* comp1  = (const float*)d_in[5];
    const float* root1  = (const float*)d_in[6];
    const float* bias1  = (const float*)d_in[7];
    const float* basis2 = (const float*)d_in[8];
    const float* comp2  = (const float*)d_in[9];
    const float* root2  = (const float*)d_in[10];
    const float* bias2  = (const float*)d_in[11];
    const float* clas_w = (const float*)d_in[12];
    const float* clas_b = (const float*)d_in[13];

    const int N = in_sizes[0] / 64;
    const int E = in_sizes[2];
    const int G = out_size / 4;
    const int* src = edge_index;
    const int* dst = edge_index + E;
    const int nbuck = (N + 255) >> 8;

    char* base = (char*)d_ws;
    size_t off = 0;
    auto carve = [&](size_t bytes) { void* p = base + off; off = (off + bytes + 15) & ~(size_t)15; return p; };
    // zero-region (one memset): cur | done | gsum — keep contiguous
    int*   cur     = (int*)carve(sizeof(int) * 256);
    int*   done    = (int*)carve(sizeof(int) * 4);
    float* gsum    = (float*)carve(sizeof(float) * (size_t)G * HH);
    size_t zbytes  = (size_t)((char*)(gsum + (size_t)G * HH) - (char*)cur);
    int*   rpflat  = (int*)carve(sizeof(int) * ((size_t)N * 4 + 4));
    int*   gstart  = (int*)carve(sizeof(int) * ((size_t)G + 1));
    int*   eidx    = (int*)carve(sizeof(int) * (size_t)E);
    int*   tmp     = (int*)carve(sizeof(int) * (size_t)nbuck * CAP);
    short* W1t     = (short*)carve(sizeof(short) * LWN);
    short* W2t     = (short*)carve(sizeof(short) * LWN);
    short* Xb1     = (short*)carve(sizeof(short) * (size_t)N * 64);
    short* H1      = (short*)carve(sizeof(short) * (size_t)N * 64);
    float* gout    = (float*)d_out;

    const int ebl = (E + EPB - 1) / EPB;
    const int wbl = (2 * LWN + 255) / 256;
    const int nb  = (N + 255) / 256;
    const int cvb = (N * 64 / 4 + 255) / 256;
    const int work_blocks = ebl + wbl + nb + cvb;
    const int layer_blocks = (N + 31) / 32;

    hipMemsetAsync(cur, 0, zbytes, stream);

    work_kernel<<<work_blocks, 256, 0, stream>>>(
        src, dst, edge_type, E, cur, tmp,
        basis1, comp1, root1, basis2, comp2, root2, W1t, W2t,
        batch, gstart, N, G, rpflat, x, Xb1, ebl, wbl, nb);
    csr_kernel<<<nbuck, 512, 0, stream>>>(cur, tmp, rpflat, eidx, N);

    layer_kernel<<<layer_blocks, 256, 0, stream>>>(
        rpflat, eidx, Xb1, W1t, bias1, H1, N, 0,
        batch, gsum, done, gstart, G, clas_w, clas_b, gout);
    layer_kernel<<<layer_blocks, 256, 0, stream>>>(
        rpflat, eidx, H1, W2t, bias2, nullptr, N, 1,
        batch, gsum, done, gstart, G, clas_w, clas_b, gout);
}

// Round 9
// 232.360 us; speedup vs baseline: 1.4549x; 1.1835x over previous
//
#include <hip/hip_runtime.h>

// H2G2: 2-layer RGCN (R=4, per-relation mean) + mean-pool + linear.
// R10 (231us, layer 47): register-resident fused layer. R11 FAILED: VGPR cap
//   -> scratch spill. R12 (229.6): channel-split wave pair; layer pinned 47.0.
// R13 FAILED: random 4B global writes = line RMW. R14 FAILED: grid.sync
//   ~80-90us each w/ idle grid. R15: CAP-bucket OK; per-element device
//   atomics FAILED (150us). R16 (219.6, BEST): memset -> work -> csr ->
//   layer1 -> layer2 -> pool.
// R17 FAILED (338): 8-edge unroll -> VGPR 140 -> occ 7.9% -> lines-in-flight
//   DOWN. MLP model CONFIRMED: layer time ~ 1/(waves x depth), saturating at
//   per-XCD L2 MSHR ceiling. FETCH 51.8MB = 8x6.4MB compulsory. Gather FROZEN
//   at 4-deep / 24 waves/CU.
// R18 (275): LDS-first pooling WORKED (WRITE 23.3->0.6MB) but elected-block
//   classifier = ~70us serial tail (1 block x uncached device-scope loads).
//   Rule: single-block epilogues w/ uncached loads cost more than a dispatch.
// R19: move per-bucket CSR INTO the layer kernel (each block's 32 nodes are
//   in ONE bucket): Phase A scans tmp bucket (L2-hot), builds cnt/off/elist
//   in LDS; Phase B = frozen gather reading LDS elist. Deletes csr dispatch +
//   gap + eidx/rpflat (6.4MB traffic). Pooling stays LDS-first in layer2;
//   classifier = separate 2-block kernel w/ NORMAL loads (kernel boundary =
//   coherence). Pipeline: memset -> work -> layer1' -> layer2' -> cls.

#define RR 4
#define HH 64
#define KK 320         // (RR+1)*HH
#define LWN (HH * KK)  // weights per layer = 20480
#define EPB 2048       // edges per bin chunk
#define CAP 6144       // per-bucket fixed capacity (mean 4096, +32 sigma)
#define NSLOT 8        // LDS pool slots (block spans <=2 graphs w.h.p.)
#define VCAP 1024      // per-block edge list cap (mean 512, +22 sigma)

using frag_ab = __attribute__((ext_vector_type(8))) short;
using frag_cd = __attribute__((ext_vector_type(4))) float;

__device__ inline short f2bf(float f) {
    unsigned u = __builtin_bit_cast(unsigned, f);
    unsigned r = u + 0x7fffu + ((u >> 16) & 1u);  // RNE
    return (short)(r >> 16);
}
__device__ inline float bf2f(short s) {
    unsigned u = ((unsigned)(unsigned short)s) << 16;
    return __builtin_bit_cast(float, u);
}

// ---- work: bin chunks | weights | gstart | x conv (one dispatch) ----
__global__ __launch_bounds__(256) void work_kernel(
    const int* __restrict__ src, const int* __restrict__ dst,
    const int* __restrict__ et, int E,
    int* __restrict__ cur, int* __restrict__ tmp,
    const float* __restrict__ basis1, const float* __restrict__ comp1, const float* __restrict__ root1,
    const float* __restrict__ basis2, const float* __restrict__ comp2, const float* __restrict__ root2,
    short* __restrict__ W1t, short* __restrict__ W2t,
    const int* __restrict__ batch, int* __restrict__ gstart, int N, int G,
    const float* __restrict__ x, short* __restrict__ Xb,
    int ebl, int wbl, int nb) {
    __shared__ int ss[256];
    __shared__ int lscan[257];
    __shared__ int lbase[256];
    __shared__ int lc2[256];
    __shared__ int sbuf[EPB];
    const int bid = blockIdx.x;
    const int t = threadIdx.x;

    if (bid < ebl) {  // ---- bin: LDS-staged bucket scatter into CAP regions ----
        const int e0 = bid * EPB;
        const int e1 = min(e0 + EPB, E);
        ss[t] = 0;
        __syncthreads();
        for (int e = e0 + t; e < e1; e += 256) atomicAdd(&ss[dst[e] >> 8], 1);
        __syncthreads();
        int v = ss[t];
        __syncthreads();
#pragma unroll
        for (int off = 1; off < 256; off <<= 1) {
            int u = (t >= off) ? ss[t - off] : 0;
            __syncthreads();
            ss[t] += u;
            __syncthreads();
        }
        lscan[t] = ss[t] - v;
        if (t == 255) lscan[256] = ss[255];
        lbase[t] = v ? t * CAP + atomicAdd(&cur[t], v) : 0;  // reserve
        lc2[t] = 0;
        __syncthreads();
        for (int e = e0 + t; e < e1; e += 256) {
            int d = dst[e];
            int b = d >> 8;
            int p = (src[e] << 10) | (et[e] << 8) | (d & 255);
            int pos = lscan[b] + atomicAdd(&lc2[b], 1);
            sbuf[pos] = p;
        }
        __syncthreads();
        int tot = lscan[256];
        for (int i = t; i < tot; i += 256) {
            int lo = 0, hi = 255;
            while (lo < hi) { int mid = (lo + hi + 1) >> 1; if (lscan[mid] <= i) lo = mid; else hi = mid - 1; }
            int idx = lbase[lo] + (i - lscan[lo]);
            if (idx - lo * CAP < CAP) tmp[idx] = sbuf[i];  // overflow shield
        }
    } else if (bid < ebl + wbl) {  // ---- weights: Wt[c*320+k] = Wstack[k][c] ----
        int w = (bid - ebl) * 256 + t;
        int layer = w / LWN;
        int rem = w - layer * LWN;
        int c = rem / KK;
        int k = rem - c * KK;
        const float* basis = layer ? basis2 : basis1;
        const float* comp  = layer ? comp2  : comp1;
        const float* root  = layer ? root2  : root1;
        short* Wt          = layer ? W2t    : W1t;
        float v;
        if (k < HH) {
            v = root[k * HH + c];
        } else {
            int r = (k >> 6) - 1, kk = k & 63;
            v = 0.f;
#pragma unroll
            for (int b = 0; b < RR; ++b) v += comp[r * RR + b] * basis[(b * HH + kk) * HH + c];
        }
        Wt[c * KK + k] = f2bf(v);
    } else if (bid < ebl + wbl + nb) {  // ---- gstart ----
        int i = (bid - ebl - wbl) * 256 + t;
        if (i < N) {
            int b1 = batch[i];
            int b0 = (i == 0) ? -1 : batch[i - 1];
            for (int g = b0 + 1; g <= b1; ++g) gstart[g] = i;
            if (i == N - 1)
                for (int g = b1 + 1; g <= G; ++g) gstart[g] = N;
        }
    } else {  // ---- convert x fp32 -> bf16 ----
        int i4 = (bid - ebl - wbl - nb) * 256 + t;
        int base = i4 * 4;
        if (base < N * 64) {
            float4 f = *(const float4*)&x[base];
            short4 s;
            s.x = f2bf(f.x); s.y = f2bf(f.y); s.z = f2bf(f.z); s.w = f2bf(f.w);
            *(short4*)&Xb[base] = s;
        }
    }
}

// ---- fused layer (R19): Phase A = in-block CSR from tmp bucket; Phase B =
//      FROZEN R16 gather (4-deep) reading LDS elist. do_pool: LDS-first
//      pooling -> gsum device atomics (no classifier tail). ----
__global__ __launch_bounds__(256) void layer_kernel(
    const int* __restrict__ curg,
    const int* __restrict__ tmp,
    const short* __restrict__ Xb,
    const short* __restrict__ Wt,
    const float* __restrict__ bias,
    short* __restrict__ out, int n, int do_pool,
    const int* __restrict__ batch, float* __restrict__ gsum) {
    __shared__ short xpack[2][64][32];  // 8KB
    __shared__ float pgs[NSLOT * 64];   // 2KB pooled partials
    __shared__ int cnt[128];            // per (node_local, rel) counts
    __shared__ int off[129];            // exclusive offsets into elist
    __shared__ int curs[128];           // scatter cursors
    __shared__ int elist[VCAP];         // 4KB: (src<<2)|et, (node,rel)-sorted
    const int t = threadIdx.x;
    const int wv = t >> 6;
    const int pair = wv >> 1;   // which 16-node group
    const int ws = wv & 1;      // channel half: 0 = quad*8, 1 = 32+quad*8
    const int l = t & 63;
    const int m = l & 15;
    const int quad = l >> 4;
    const int node0 = blockIdx.x * 32;
    const int node = node0 + pair * 16 + m;
    const bool valid = node < n;

    // ---- Phase A: in-block CSR build from tmp bucket ----
    const int b = node0 >> 8;
    const int dl0 = node0 & 255;
    const int tb = b * CAP;
    const int len = min(curg[b], CAP);

    for (int i = t; i < 128; i += 256) cnt[i] = 0;
    if (do_pool)
        for (int i = t; i < NSLOT * 64; i += 256) pgs[i] = 0.f;
    __syncthreads();
    for (int i = t; i < len; i += 256) {
        int e = tmp[tb + i];
        int w = (e & 255) - dl0;
        if ((unsigned)w < 32u) atomicAdd(&cnt[(w << 2) | ((e >> 8) & 3)], 1);
    }
    __syncthreads();
    if (t < 128) off[t] = cnt[t];
    __syncthreads();
#pragma unroll
    for (int o = 1; o < 128; o <<= 1) {
        int u = (t < 128 && t >= o) ? off[t - o] : 0;
        __syncthreads();
        if (t < 128) off[t] += u;
        __syncthreads();
    }
    if (t < 128) {
        int ex = off[t] - cnt[t];
        off[t] = ex;
        curs[t] = ex;
        if (t == 127) off[128] = ex + cnt[127];
    }
    __syncthreads();
    for (int i = t; i < len; i += 256) {
        int e = tmp[tb + i];
        int w = (e & 255) - dl0;
        if ((unsigned)w < 32u) {
            int pos = atomicAdd(&curs[(w << 2) | ((e >> 8) & 3)], 1);
            if (pos < VCAP) elist[pos] = ((e >> 10) << 2) | ((e >> 8) & 3);
        }
    }
    __syncthreads();

    // ---- Phase B: gather (FROZEN 4-deep structure; elist in LDS) ----
    float acc[4][8];
#pragma unroll
    for (int r = 0; r < 4; ++r)
#pragma unroll
        for (int j = 0; j < 8; ++j) acc[r][j] = 0.f;

    const int w4 = ((pair << 4) | m) << 2;
    const int k0 = min(off[w4], VCAP);
    const int k1 = min(off[w4 + 4], VCAP);
    float4 iv;
    iv.x = 1.0f / fmaxf((float)cnt[w4 + 0], 1.0f);
    iv.y = 1.0f / fmaxf((float)cnt[w4 + 1], 1.0f);
    iv.z = 1.0f / fmaxf((float)cnt[w4 + 2], 1.0f);
    iv.w = 1.0f / fmaxf((float)cnt[w4 + 3], 1.0f);
    const short* xbq = Xb + ws * 32 + quad * 8;

#define ACC(P, F)                                                             \
    {                                                                         \
        int r_ = (P) & 3;                                                     \
        float s0_ = (r_ == 0) ? 1.f : 0.f;                                    \
        float s1_ = (r_ == 1) ? 1.f : 0.f;                                    \
        float s2_ = (r_ == 2) ? 1.f : 0.f;                                    \
        float s3_ = (r_ == 3) ? 1.f : 0.f;                                    \
        _Pragma("unroll") for (int j = 0; j < 8; ++j) {                       \
            float v_ = bf2f((F)[j]);                                          \
            acc[0][j] += v_ * s0_;                                            \
            acc[1][j] += v_ * s1_;                                            \
            acc[2][j] += v_ * s2_;                                            \
            acc[3][j] += v_ * s3_;                                            \
        }                                                                     \
    }

    int k = k0;
    for (; k + 3 < k1; k += 4) {  // 4 edges in flight (MSHR-optimal)
        int p0 = elist[k];
        int p1 = elist[k + 1];
        int p2 = elist[k + 2];
        int p3 = elist[k + 3];
        const short* a0p = xbq + (size_t)(p0 >> 2) * 64;
        const short* a1p = xbq + (size_t)(p1 >> 2) * 64;
        const short* a2p = xbq + (size_t)(p2 >> 2) * 64;
        const short* a3p = xbq + (size_t)(p3 >> 2) * 64;
        frag_ab f0 = *(const frag_ab*)a0p;
        frag_ab f1 = *(const frag_ab*)a1p;
        frag_ab f2 = *(const frag_ab*)a2p;
        frag_ab f3 = *(const frag_ab*)a3p;
        ACC(p0, f0)
        ACC(p1, f1)
        ACC(p2, f2)
        ACC(p3, f3)
    }
    for (; k < k1; ++k) {
        int p0 = elist[k];
        const short* a0p = xbq + (size_t)(p0 >> 2) * 64;
        frag_ab f0 = *(const frag_ab*)a0p;
        ACC(p0, f0)
    }
#undef ACC

    frag_ab y[4];
    {
        float s0 = iv.x, s1 = iv.y, s2 = iv.z, s3 = iv.w;
#pragma unroll
        for (int j = 0; j < 8; ++j) {
            y[0][j] = f2bf(acc[0][j] * s0);
            y[1][j] = f2bf(acc[1][j] * s1);
            y[2][j] = f2bf(acc[2][j] * s2);
            y[3][j] = f2bf(acc[3][j] * s3);
        }
    }

    if (ws == 1) {
#pragma unroll
        for (int r = 0; r < 4; ++r)
            *(frag_ab*)&xpack[pair][l][r * 8] = y[r];
    }
    __syncthreads();
    if (!do_pool && ws == 1) return;

    const int nrow_base = node0 + pair * 16 + quad * 4;
    const int batch_base = do_pool ? batch[node0] : 0;

    if (ws == 0) {
        frag_ab a[10];
        a[0] = frag_ab{};
        a[1] = frag_ab{};
        if (valid) {
            const short* xr = Xb + (size_t)node * 64 + quad * 8;
            a[0] = *(const frag_ab*)xr;
            a[1] = *(const frag_ab*)(xr + 32);
        }
#pragma unroll
        for (int r = 0; r < 4; ++r) {
            a[2 + 2 * r] = y[r];
            a[3 + 2 * r] = *(const frag_ab*)&xpack[pair][l][r * 8];
        }

        int bv4[4];
        if (do_pool) {
            if (nrow_base + 3 < n) {
                int4 bb = *(const int4*)&batch[nrow_base];
                bv4[0] = bb.x; bv4[1] = bb.y; bv4[2] = bb.z; bv4[3] = bb.w;
            } else {
#pragma unroll
                for (int r = 0; r < 4; ++r)
                    bv4[r] = (nrow_base + r < n) ? batch[nrow_base + r] : 0;
            }
        }

#pragma unroll
        for (int ct = 0; ct < 4; ++ct) {
            const short* bp = Wt + (size_t)(ct * 16 + m) * KK + quad * 8;
            frag_cd c = {0.f, 0.f, 0.f, 0.f};
#pragma unroll
            for (int f = 0; f < 10; ++f) {
                frag_ab bf = *(const frag_ab*)(bp + f * 32);
                c = __builtin_amdgcn_mfma_f32_16x16x32_bf16(a[f], bf, c, 0, 0, 0);
            }
            int col = ct * 16 + m;
            float bv = bias[col];
            if (do_pool) {
#pragma unroll
                for (int r = 0; r < 4; ++r) {
                    int nr = nrow_base + r;
                    if (nr < n) {
                        float v = fmaxf(c[r] + bv, 0.f);
                        int g = bv4[r] - batch_base;
                        if (g < NSLOT)
                            atomicAdd(&pgs[g * 64 + col], v);
                        else
                            atomicAdd(&gsum[(size_t)bv4[r] * 64 + col], v);
                    }
                }
            } else {
#pragma unroll
                for (int r = 0; r < 4; ++r) {
                    int nr = nrow_base + r;
                    if (nr < n) out[(size_t)nr * 64 + col] = f2bf(fmaxf(c[r] + bv, 0.f));
                }
            }
        }
    }

    if (do_pool) {
        __syncthreads();
        // flush block partials: ~(gspan+1)*64 device-scope atomics per block
        int node_last = min(node0 + 31, n - 1);
        int gspan = batch[node_last] - batch_base;
        for (int i = t; i < NSLOT * 64; i += 256) {
            int s = i >> 6;
            if (s <= gspan) {
                float v = pgs[i];
                if (v != 0.f) atomicAdd(&gsum[(size_t)(batch_base + s) * 64 + (i & 63)], v);
            }
        }
    }
}

// ---- cls: mean + linear from gsum (normal loads; kernel boundary = coherence) ----
__global__ __launch_bounds__(256) void cls_kernel(const float* __restrict__ gsum,
                                                  const int* __restrict__ gstart,
                                                  const float* __restrict__ w,
                                                  const float* __restrict__ bcls,
                                                  float* __restrict__ out, int G) {
    const int g = blockIdx.x * 256 + threadIdx.x;
    if (g >= G) return;
    int s = gstart[g], e = gstart[g + 1];
    float invc = 1.0f / fmaxf((float)(e - s), 1.0f);
    float o0 = 0.f, o1 = 0.f, o2 = 0.f, o3 = 0.f;
    const float* gr = gsum + (size_t)g * 64;
#pragma unroll 8
    for (int hh = 0; hh < 64; ++hh) {
        float mm = gr[hh] * invc;
        float4 wr = *(const float4*)&w[hh * 4];
        o0 += mm * wr.x;
        o1 += mm * wr.y;
        o2 += mm * wr.z;
        o3 += mm * wr.w;
    }
    float4 o = make_float4(o0 + bcls[0], o1 + bcls[1], o2 + bcls[2], o3 + bcls[3]);
    *(float4*)&out[g * 4] = o;
}

extern "C" void kernel_launch(void* const* d_in, const int* in_sizes, int n_in,
                              void* d_out, int out_size, void* d_ws, size_t ws_size,
                              hipStream_t stream) {
    const float* x        = (const float*)d_in[0];
    const int* edge_index = (const int*)d_in[1];
    const int* edge_type  = (const int*)d_in[2];
    const int* batch      = (const int*)d_in[3];
    const float* basis1 = (const float*)d_in[4];
    const float* comp1  = (const float*)d_in[5];
    const float* root1  = (const float*)d_in[6];
    const float* bias1  = (const float*)d_in[7];
    const float* basis2 = (const float*)d_in[8];
    const float* comp2  = (const float*)d_in[9];
    const float* root2  = (const float*)d_in[10];
    const float* bias2  = (const float*)d_in[11];
    const float* clas_w = (const float*)d_in[12];
    const float* clas_b = (const float*)d_in[13];

    const int N = in_sizes[0] / 64;
    const int E = in_sizes[2];
    const int G = out_size / 4;
    const int* src = edge_index;
    const int* dst = edge_index + E;
    const int nbuck = (N + 255) >> 8;

    char* base = (char*)d_ws;
    size_t off = 0;
    auto carve = [&](size_t bytes) { void* p = base + off; off = (off + bytes + 15) & ~(size_t)15; return p; };
    // zero-region (one memset): cur | gsum — keep contiguous
    int*   cur     = (int*)carve(sizeof(int) * 256);
    float* gsum    = (float*)carve(sizeof(float) * (size_t)G * HH);
    size_t zbytes  = (size_t)((char*)(gsum + (size_t)G * HH) - (char*)cur);
    int*   gstart  = (int*)carve(sizeof(int) * ((size_t)G + 1));
    int*   tmp     = (int*)carve(sizeof(int) * (size_t)nbuck * CAP);
    short* W1t     = (short*)carve(sizeof(short) * LWN);
    short* W2t     = (short*)carve(sizeof(short) * LWN);
    short* Xb1     = (short*)carve(sizeof(short) * (size_t)N * 64);
    short* H1      = (short*)carve(sizeof(short) * (size_t)N * 64);
    float* gout    = (float*)d_out;

    const int ebl = (E + EPB - 1) / EPB;
    const int wbl = (2 * LWN + 255) / 256;
    const int nb  = (N + 255) / 256;
    const int cvb = (N * 64 / 4 + 255) / 256;
    const int work_blocks = ebl + wbl + nb + cvb;
    const int layer_blocks = (N + 31) / 32;

    hipMemsetAsync(cur, 0, zbytes, stream);

    work_kernel<<<work_blocks, 256, 0, stream>>>(
        src, dst, edge_type, E, cur, tmp,
        basis1, comp1, root1, basis2, comp2, root2, W1t, W2t,
        batch, gstart, N, G, x, Xb1, ebl, wbl, nb);

    layer_kernel<<<layer_blocks, 256, 0, stream>>>(
        cur, tmp, Xb1, W1t, bias1, H1, N, 0, batch, gsum);
    layer_kernel<<<layer_blocks, 256, 0, stream>>>(
        cur, tmp, H1, W2t, bias2, nullptr, N, 1, batch, gsum);

    cls_kernel<<<(G + 255) / 256, 256, 0, stream>>>(
        gsum, gstart, clas_w, clas_b, gout, G);
}

// Round 10
// 218.281 us; speedup vs baseline: 1.5487x; 1.0645x over previous
//
#include <hip/hip_runtime.h>

// H2G2: 2-layer RGCN (R=4, per-relation mean) + mean-pool + linear.
// R10 (231us, layer 47): register-resident fused layer. R11 FAILED: VGPR cap
//   -> scratch spill. R12 (229.6): channel-split wave pair; layer pinned 47.0.
// R13 FAILED: random 4B global writes = line RMW. R14 FAILED: grid.sync
//   ~80-90us each w/ idle grid. R15: CAP-bucket OK; per-element device
//   atomics FAILED. R16 (219.6): memset -> work -> csr -> L1 -> L2 -> pool.
// R17 FAILED: 8-edge unroll -> VGPR 140 -> occ crash. MLP model CONFIRMED:
//   layer time ~ 1/(waves x in-flight), at per-XCD L2 MSHR ceiling. Gather
//   FROZEN at 4-deep / 24 waves/CU. FETCH 52MB compulsory.
// R18 (275): LDS-first pooling WORKED; 1-block uncached classifier = 70us
//   serial tail. Rule: kernel boundary beats single-block uncached epilogue.
// R19 (232.4): in-layer Phase A CSR works but was paid TWICE (+17us/layer:
//   8 blocks/bucket x 2 scans of 4096 entries; FETCH +8.7MB). Pool fusion +
//   cls kernel validated (layer2 WRITE 0.5MB, == layer1 time).
// R20: CSR computed ONCE: layer_build (L1) = Phase A + persist rp4/kend/
//   eidx_g (fixed VCAP/block regions, coalesced, overlapped w/ gather) +
//   frozen gather. layer_read (L2) = R16-style gather from persisted CSR
//   (no Phase A) + pgs pooling. memset -> work -> build -> read -> cls.

#define RR 4
#define HH 64
#define KK 320         // (RR+1)*HH
#define LWN (HH * KK)  // weights per layer = 20480
#define EPB 2048       // edges per bin chunk
#define CAP 6144       // per-bucket fixed capacity (mean 4096, +32 sigma)
#define NSLOT 8        // LDS pool slots (block spans <=2 graphs w.h.p.)
#define VCAP 1024      // per-block edge list cap (mean 512, +22 sigma)

using frag_ab = __attribute__((ext_vector_type(8))) short;
using frag_cd = __attribute__((ext_vector_type(4))) float;

__device__ inline short f2bf(float f) {
    unsigned u = __builtin_bit_cast(unsigned, f);
    unsigned r = u + 0x7fffu + ((u >> 16) & 1u);  // RNE
    return (short)(r >> 16);
}
__device__ inline float bf2f(short s) {
    unsigned u = ((unsigned)(unsigned short)s) << 16;
    return __builtin_bit_cast(float, u);
}

// ---- shared gather + MFMA macro pieces ----
#define ACCM(P, F)                                                            \
    {                                                                         \
        int r_ = (P) & 3;                                                     \
        float s0_ = (r_ == 0) ? 1.f : 0.f;                                    \
        float s1_ = (r_ == 1) ? 1.f : 0.f;                                    \
        float s2_ = (r_ == 2) ? 1.f : 0.f;                                    \
        float s3_ = (r_ == 3) ? 1.f : 0.f;                                    \
        _Pragma("unroll") for (int j = 0; j < 8; ++j) {                       \
            float v_ = bf2f((F)[j]);                                          \
            acc[0][j] += v_ * s0_;                                            \
            acc[1][j] += v_ * s1_;                                            \
            acc[2][j] += v_ * s2_;                                            \
            acc[3][j] += v_ * s3_;                                            \
        }                                                                     \
    }

// ---- work: bin chunks | weights | gstart | x conv (one dispatch) ----
__global__ __launch_bounds__(256) void work_kernel(
    const int* __restrict__ src, const int* __restrict__ dst,
    const int* __restrict__ et, int E,
    int* __restrict__ cur, int* __restrict__ tmp,
    const float* __restrict__ basis1, const float* __restrict__ comp1, const float* __restrict__ root1,
    const float* __restrict__ basis2, const float* __restrict__ comp2, const float* __restrict__ root2,
    short* __restrict__ W1t, short* __restrict__ W2t,
    const int* __restrict__ batch, int* __restrict__ gstart, int N, int G,
    const float* __restrict__ x, short* __restrict__ Xb,
    int ebl, int wbl, int nb) {
    __shared__ int ss[256];
    __shared__ int lscan[257];
    __shared__ int lbase[256];
    __shared__ int lc2[256];
    __shared__ int sbuf[EPB];
    const int bid = blockIdx.x;
    const int t = threadIdx.x;

    if (bid < ebl) {  // ---- bin: LDS-staged bucket scatter into CAP regions ----
        const int e0 = bid * EPB;
        const int e1 = min(e0 + EPB, E);
        ss[t] = 0;
        __syncthreads();
        for (int e = e0 + t; e < e1; e += 256) atomicAdd(&ss[dst[e] >> 8], 1);
        __syncthreads();
        int v = ss[t];
        __syncthreads();
#pragma unroll
        for (int off = 1; off < 256; off <<= 1) {
            int u = (t >= off) ? ss[t - off] : 0;
            __syncthreads();
            ss[t] += u;
            __syncthreads();
        }
        lscan[t] = ss[t] - v;
        if (t == 255) lscan[256] = ss[255];
        lbase[t] = v ? t * CAP + atomicAdd(&cur[t], v) : 0;  // reserve
        lc2[t] = 0;
        __syncthreads();
        for (int e = e0 + t; e < e1; e += 256) {
            int d = dst[e];
            int b = d >> 8;
            int p = (src[e] << 10) | (et[e] << 8) | (d & 255);
            int pos = lscan[b] + atomicAdd(&lc2[b], 1);
            sbuf[pos] = p;
        }
        __syncthreads();
        int tot = lscan[256];
        for (int i = t; i < tot; i += 256) {
            int lo = 0, hi = 255;
            while (lo < hi) { int mid = (lo + hi + 1) >> 1; if (lscan[mid] <= i) lo = mid; else hi = mid - 1; }
            int idx = lbase[lo] + (i - lscan[lo]);
            if (idx - lo * CAP < CAP) tmp[idx] = sbuf[i];  // overflow shield
        }
    } else if (bid < ebl + wbl) {  // ---- weights: Wt[c*320+k] = Wstack[k][c] ----
        int w = (bid - ebl) * 256 + t;
        int layer = w / LWN;
        int rem = w - layer * LWN;
        int c = rem / KK;
        int k = rem - c * KK;
        const float* basis = layer ? basis2 : basis1;
        const float* comp  = layer ? comp2  : comp1;
        const float* root  = layer ? root2  : root1;
        short* Wt          = layer ? W2t    : W1t;
        float v;
        if (k < HH) {
            v = root[k * HH + c];
        } else {
            int r = (k >> 6) - 1, kk = k & 63;
            v = 0.f;
#pragma unroll
            for (int b = 0; b < RR; ++b) v += comp[r * RR + b] * basis[(b * HH + kk) * HH + c];
        }
        Wt[c * KK + k] = f2bf(v);
    } else if (bid < ebl + wbl + nb) {  // ---- gstart ----
        int i = (bid - ebl - wbl) * 256 + t;
        if (i < N) {
            int b1 = batch[i];
            int b0 = (i == 0) ? -1 : batch[i - 1];
            for (int g = b0 + 1; g <= b1; ++g) gstart[g] = i;
            if (i == N - 1)
                for (int g = b1 + 1; g <= G; ++g) gstart[g] = N;
        }
    } else {  // ---- convert x fp32 -> bf16 ----
        int i4 = (bid - ebl - wbl - nb) * 256 + t;
        int base = i4 * 4;
        if (base < N * 64) {
            float4 f = *(const float4*)&x[base];
            short4 s;
            s.x = f2bf(f.x); s.y = f2bf(f.y); s.z = f2bf(f.z); s.w = f2bf(f.w);
            *(short4*)&Xb[base] = s;
        }
    }
}

// ---- layer_build (L1): Phase A CSR from tmp bucket -> persist rp4/kend/
//      eidx_g; Phase B = FROZEN 4-deep gather from LDS elist. ----
__global__ __launch_bounds__(256) void layer_build_kernel(
    const int* __restrict__ curg,
    const int* __restrict__ tmp,
    const short* __restrict__ Xb,
    const short* __restrict__ Wt,
    const float* __restrict__ bias,
    short* __restrict__ out, int n,
    int4* __restrict__ rp4g, int* __restrict__ kendg,
    int* __restrict__ eidxg) {
    __shared__ short xpack[2][64][32];  // 8KB
    __shared__ int cnt[128];
    __shared__ int off[129];
    __shared__ int curs[128];
    __shared__ int elist[VCAP];         // 4KB
    const int t = threadIdx.x;
    const int wv = t >> 6;
    const int pair = wv >> 1;
    const int ws = wv & 1;
    const int l = t & 63;
    const int m = l & 15;
    const int quad = l >> 4;
    const int node0 = blockIdx.x * 32;
    const int node = node0 + pair * 16 + m;
    const bool valid = node < n;

    // ---- Phase A ----
    const int b = node0 >> 8;
    const int dl0 = node0 & 255;
    const int tb = b * CAP;
    const int len = min(curg[b], CAP);

    for (int i = t; i < 128; i += 256) cnt[i] = 0;
    __syncthreads();
    for (int i = t; i < len; i += 256) {
        int e = tmp[tb + i];
        int w = (e & 255) - dl0;
        if ((unsigned)w < 32u) atomicAdd(&cnt[(w << 2) | ((e >> 8) & 3)], 1);
    }
    __syncthreads();
    if (t < 128) off[t] = cnt[t];
    __syncthreads();
#pragma unroll
    for (int o = 1; o < 128; o <<= 1) {
        int u = (t < 128 && t >= o) ? off[t - o] : 0;
        __syncthreads();
        if (t < 128) off[t] += u;
        __syncthreads();
    }
    if (t < 128) {
        int ex = off[t] - cnt[t];
        off[t] = ex;
        curs[t] = ex;
        if (t == 127) off[128] = ex + cnt[127];
    }
    __syncthreads();
    for (int i = t; i < len; i += 256) {
        int e = tmp[tb + i];
        int w = (e & 255) - dl0;
        if ((unsigned)w < 32u) {
            int pos = atomicAdd(&curs[(w << 2) | ((e >> 8) & 3)], 1);
            if (pos < VCAP) elist[pos] = ((e >> 10) << 2) | ((e >> 8) & 3);
        }
    }
    __syncthreads();

    // ---- persist CSR (overlaps with Phase B issue) ----
    const int eb = blockIdx.x * VCAP;
    if (t < 32 && node0 + t < n) {
        int c4 = t << 2;
        rp4g[node0 + t] = make_int4(eb + min(off[c4], VCAP), eb + min(off[c4 + 1], VCAP),
                                    eb + min(off[c4 + 2], VCAP), eb + min(off[c4 + 3], VCAP));
        kendg[node0 + t] = eb + min(off[c4 + 4], VCAP);
    }
    {
        int fill = min(off[128], VCAP);
        for (int i = t; i < fill; i += 256) eidxg[eb + i] = elist[i];
    }

    // ---- Phase B: FROZEN gather from LDS elist ----
    float acc[4][8];
#pragma unroll
    for (int r = 0; r < 4; ++r)
#pragma unroll
        for (int j = 0; j < 8; ++j) acc[r][j] = 0.f;

    const int w4 = ((pair << 4) | m) << 2;
    const int k0 = min(off[w4], VCAP);
    const int k1 = min(off[w4 + 4], VCAP);
    float4 iv;
    iv.x = 1.0f / fmaxf((float)cnt[w4 + 0], 1.0f);
    iv.y = 1.0f / fmaxf((float)cnt[w4 + 1], 1.0f);
    iv.z = 1.0f / fmaxf((float)cnt[w4 + 2], 1.0f);
    iv.w = 1.0f / fmaxf((float)cnt[w4 + 3], 1.0f);
    const short* xbq = Xb + ws * 32 + quad * 8;

    int k = k0;
    for (; k + 3 < k1; k += 4) {
        int p0 = elist[k];
        int p1 = elist[k + 1];
        int p2 = elist[k + 2];
        int p3 = elist[k + 3];
        const short* a0p = xbq + (size_t)(p0 >> 2) * 64;
        const short* a1p = xbq + (size_t)(p1 >> 2) * 64;
        const short* a2p = xbq + (size_t)(p2 >> 2) * 64;
        const short* a3p = xbq + (size_t)(p3 >> 2) * 64;
        frag_ab f0 = *(const frag_ab*)a0p;
        frag_ab f1 = *(const frag_ab*)a1p;
        frag_ab f2 = *(const frag_ab*)a2p;
        frag_ab f3 = *(const frag_ab*)a3p;
        ACCM(p0, f0)
        ACCM(p1, f1)
        ACCM(p2, f2)
        ACCM(p3, f3)
    }
    for (; k < k1; ++k) {
        int p0 = elist[k];
        const short* a0p = xbq + (size_t)(p0 >> 2) * 64;
        frag_ab f0 = *(const frag_ab*)a0p;
        ACCM(p0, f0)
    }

    frag_ab y[4];
    {
        float s0 = iv.x, s1 = iv.y, s2 = iv.z, s3 = iv.w;
#pragma unroll
        for (int j = 0; j < 8; ++j) {
            y[0][j] = f2bf(acc[0][j] * s0);
            y[1][j] = f2bf(acc[1][j] * s1);
            y[2][j] = f2bf(acc[2][j] * s2);
            y[3][j] = f2bf(acc[3][j] * s3);
        }
    }

    if (ws == 1) {
#pragma unroll
        for (int r = 0; r < 4; ++r)
            *(frag_ab*)&xpack[pair][l][r * 8] = y[r];
    }
    __syncthreads();
    if (ws == 1) return;

    frag_ab a[10];
    a[0] = frag_ab{};
    a[1] = frag_ab{};
    if (valid) {
        const short* xr = Xb + (size_t)node * 64 + quad * 8;
        a[0] = *(const frag_ab*)xr;
        a[1] = *(const frag_ab*)(xr + 32);
    }
#pragma unroll
    for (int r = 0; r < 4; ++r) {
        a[2 + 2 * r] = y[r];
        a[3 + 2 * r] = *(const frag_ab*)&xpack[pair][l][r * 8];
    }

    const int nrow_base = node0 + pair * 16 + quad * 4;
#pragma unroll
    for (int ct = 0; ct < 4; ++ct) {
        const short* bp = Wt + (size_t)(ct * 16 + m) * KK + quad * 8;
        frag_cd c = {0.f, 0.f, 0.f, 0.f};
#pragma unroll
        for (int f = 0; f < 10; ++f) {
            frag_ab bf = *(const frag_ab*)(bp + f * 32);
            c = __builtin_amdgcn_mfma_f32_16x16x32_bf16(a[f], bf, c, 0, 0, 0);
        }
        int col = ct * 16 + m;
        float bv = bias[col];
#pragma unroll
        for (int r = 0; r < 4; ++r) {
            int nr = nrow_base + r;
            if (nr < n) out[(size_t)nr * 64 + col] = f2bf(fmaxf(c[r] + bv, 0.f));
        }
    }
}

// ---- layer_read (L2): R16-style gather from persisted CSR (no Phase A) +
//      LDS-first pooling -> gsum. ----
__global__ __launch_bounds__(256) void layer_read_kernel(
    const int4* __restrict__ rp4g, const int* __restrict__ kendg,
    const int* __restrict__ eidxg,
    const short* __restrict__ Xb,
    const short* __restrict__ Wt,
    const float* __restrict__ bias,
    int n, const int* __restrict__ batch, float* __restrict__ gsum) {
    __shared__ short xpack[2][64][32];  // 8KB
    __shared__ float pgs[NSLOT * 64];   // 2KB
    const int t = threadIdx.x;
    const int wv = t >> 6;
    const int pair = wv >> 1;
    const int ws = wv & 1;
    const int l = t & 63;
    const int m = l & 15;
    const int quad = l >> 4;
    const int node0 = blockIdx.x * 32;
    const int node = node0 + pair * 16 + m;
    const bool valid = node < n;

    for (int i = t; i < NSLOT * 64; i += 256) pgs[i] = 0.f;

    float acc[4][8];
#pragma unroll
    for (int r = 0; r < 4; ++r)
#pragma unroll
        for (int j = 0; j < 8; ++j) acc[r][j] = 0.f;

    int k0 = 0, k1 = 0;
    float4 iv = make_float4(0.f, 0.f, 0.f, 0.f);
    if (valid) {
        int4 r4 = rp4g[node];
        int kend = kendg[node];
        k0 = r4.x;
        k1 = kend;
        iv.x = 1.0f / fmaxf((float)(r4.y - r4.x), 1.0f);
        iv.y = 1.0f / fmaxf((float)(r4.z - r4.y), 1.0f);
        iv.z = 1.0f / fmaxf((float)(r4.w - r4.z), 1.0f);
        iv.w = 1.0f / fmaxf((float)(kend - r4.w), 1.0f);
    }
    const short* xbq = Xb + ws * 32 + quad * 8;

    int k = k0;
    for (; k + 3 < k1; k += 4) {  // FROZEN 4-deep
        int p0 = eidxg[k];
        int p1 = eidxg[k + 1];
        int p2 = eidxg[k + 2];
        int p3 = eidxg[k + 3];
        const short* a0p = xbq + (size_t)(p0 >> 2) * 64;
        const short* a1p = xbq + (size_t)(p1 >> 2) * 64;
        const short* a2p = xbq + (size_t)(p2 >> 2) * 64;
        const short* a3p = xbq + (size_t)(p3 >> 2) * 64;
        frag_ab f0 = *(const frag_ab*)a0p;
        frag_ab f1 = *(const frag_ab*)a1p;
        frag_ab f2 = *(const frag_ab*)a2p;
        frag_ab f3 = *(const frag_ab*)a3p;
        ACCM(p0, f0)
        ACCM(p1, f1)
        ACCM(p2, f2)
        ACCM(p3, f3)
    }
    for (; k < k1; ++k) {
        int p0 = eidxg[k];
        const short* a0p = xbq + (size_t)(p0 >> 2) * 64;
        frag_ab f0 = *(const frag_ab*)a0p;
        ACCM(p0, f0)
    }

    frag_ab y[4];
    {
        float s0 = iv.x, s1 = iv.y, s2 = iv.z, s3 = iv.w;
#pragma unroll
        for (int j = 0; j < 8; ++j) {
            y[0][j] = f2bf(acc[0][j] * s0);
            y[1][j] = f2bf(acc[1][j] * s1);
            y[2][j] = f2bf(acc[2][j] * s2);
            y[3][j] = f2bf(acc[3][j] * s3);
        }
    }

    if (ws == 1) {
#pragma unroll
        for (int r = 0; r < 4; ++r)
            *(frag_ab*)&xpack[pair][l][r * 8] = y[r];
    }
    __syncthreads();

    const int nrow_base = node0 + pair * 16 + quad * 4;
    const int batch_base = batch[node0];

    if (ws == 0) {
        frag_ab a[10];
        a[0] = frag_ab{};
        a[1] = frag_ab{};
        if (valid) {
            const short* xr = Xb + (size_t)node * 64 + quad * 8;
            a[0] = *(const frag_ab*)xr;
            a[1] = *(const frag_ab*)(xr + 32);
        }
#pragma unroll
        for (int r = 0; r < 4; ++r) {
            a[2 + 2 * r] = y[r];
            a[3 + 2 * r] = *(const frag_ab*)&xpack[pair][l][r * 8];
        }

        int bv4[4];
        if (nrow_base + 3 < n) {
            int4 bb = *(const int4*)&batch[nrow_base];
            bv4[0] = bb.x; bv4[1] = bb.y; bv4[2] = bb.z; bv4[3] = bb.w;
        } else {
#pragma unroll
            for (int r = 0; r < 4; ++r)
                bv4[r] = (nrow_base + r < n) ? batch[nrow_base + r] : 0;
        }

#pragma unroll
        for (int ct = 0; ct < 4; ++ct) {
            const short* bp = Wt + (size_t)(ct * 16 + m) * KK + quad * 8;
            frag_cd c = {0.f, 0.f, 0.f, 0.f};
#pragma unroll
            for (int f = 0; f < 10; ++f) {
                frag_ab bf = *(const frag_ab*)(bp + f * 32);
                c = __builtin_amdgcn_mfma_f32_16x16x32_bf16(a[f], bf, c, 0, 0, 0);
            }
            int col = ct * 16 + m;
            float bv = bias[col];
#pragma unroll
            for (int r = 0; r < 4; ++r) {
                int nr = nrow_base + r;
                if (nr < n) {
                    float v = fmaxf(c[r] + bv, 0.f);
                    int g = bv4[r] - batch_base;
                    if (g < NSLOT)
                        atomicAdd(&pgs[g * 64 + col], v);
                    else
                        atomicAdd(&gsum[(size_t)bv4[r] * 64 + col], v);
                }
            }
        }
    }

    __syncthreads();
    int node_last = min(node0 + 31, n - 1);
    int gspan = batch[node_last] - batch_base;
    for (int i = t; i < NSLOT * 64; i += 256) {
        int s = i >> 6;
        if (s <= gspan) {
            float v = pgs[i];
            if (v != 0.f) atomicAdd(&gsum[(size_t)(batch_base + s) * 64 + (i & 63)], v);
        }
    }
}

// ---- cls: mean + linear from gsum (normal loads; kernel boundary = coherence) ----
__global__ __launch_bounds__(256) void cls_kernel(const float* __restrict__ gsum,
                                                  const int* __restrict__ gstart,
                                                  const float* __restrict__ w,
                                                  const float* __restrict__ bcls,
                                                  float* __restrict__ out, int G) {
    const int g = blockIdx.x * 256 + threadIdx.x;
    if (g >= G) return;
    int s = gstart[g], e = gstart[g + 1];
    float invc = 1.0f / fmaxf((float)(e - s), 1.0f);
    float o0 = 0.f, o1 = 0.f, o2 = 0.f, o3 = 0.f;
    const float* gr = gsum + (size_t)g * 64;
#pragma unroll 8
    for (int hh = 0; hh < 64; ++hh) {
        float mm = gr[hh] * invc;
        float4 wr = *(const float4*)&w[hh * 4];
        o0 += mm * wr.x;
        o1 += mm * wr.y;
        o2 += mm * wr.z;
        o3 += mm * wr.w;
    }
    float4 o = make_float4(o0 + bcls[0], o1 + bcls[1], o2 + bcls[2], o3 + bcls[3]);
    *(float4*)&out[g * 4] = o;
}

extern "C" void kernel_launch(void* const* d_in, const int* in_sizes, int n_in,
                              void* d_out, int out_size, void* d_ws, size_t ws_size,
                              hipStream_t stream) {
    const float* x        = (const float*)d_in[0];
    const int* edge_index = (const int*)d_in[1];
    const int* edge_type  = (const int*)d_in[2];
    const int* batch      = (const int*)d_in[3];
    const float* basis1 = (const float*)d_in[4];
    const float* comp1  = (const float*)d_in[5];
    const float* root1  = (const float*)d_in[6];
    const float* bias1  = (const float*)d_in[7];
    const float* basis2 = (const float*)d_in[8];
    const float* comp2  = (const float*)d_in[9];
    const float* root2  = (const float*)d_in[10];
    const float* bias2  = (const float*)d_in[11];
    const float* clas_w = (const float*)d_in[12];
    const float* clas_b = (const float*)d_in[13];

    const int N = in_sizes[0] / 64;
    const int E = in_sizes[2];
    const int G = out_size / 4;
    const int* src = edge_index;
    const int* dst = edge_index + E;
    const int nbuck = (N + 255) >> 8;
    const int layer_blocks = (N + 31) / 32;

    char* base = (char*)d_ws;
    size_t off = 0;
    auto carve = [&](size_t bytes) { void* p = base + off; off = (off + bytes + 15) & ~(size_t)15; return p; };
    // zero-region (one memset): cur | gsum — keep contiguous
    int*   cur     = (int*)carve(sizeof(int) * 256);
    float* gsum    = (float*)carve(sizeof(float) * (size_t)G * HH);
    size_t zbytes  = (size_t)((char*)(gsum + (size_t)G * HH) - (char*)cur);
    int*   gstart  = (int*)carve(sizeof(int) * ((size_t)G + 1));
    int*   tmp     = (int*)carve(sizeof(int) * (size_t)nbuck * CAP);
    int4*  rp4g    = (int4*)carve(sizeof(int4) * (size_t)N);
    int*   kendg   = (int*)carve(sizeof(int) * (size_t)N);
    int*   eidxg   = (int*)carve(sizeof(int) * (size_t)layer_blocks * VCAP);
    short* W1t     = (short*)carve(sizeof(short) * LWN);
    short* W2t     = (short*)carve(sizeof(short) * LWN);
    short* Xb1     = (short*)carve(sizeof(short) * (size_t)N * 64);
    short* H1      = (short*)carve(sizeof(short) * (size_t)N * 64);
    float* gout    = (float*)d_out;

    const int ebl = (E + EPB - 1) / EPB;
    const int wbl = (2 * LWN + 255) / 256;
    const int nb  = (N + 255) / 256;
    const int cvb = (N * 64 / 4 + 255) / 256;
    const int work_blocks = ebl + wbl + nb + cvb;

    hipMemsetAsync(cur, 0, zbytes, stream);

    work_kernel<<<work_blocks, 256, 0, stream>>>(
        src, dst, edge_type, E, cur, tmp,
        basis1, comp1, root1, basis2, comp2, root2, W1t, W2t,
        batch, gstart, N, G, x, Xb1, ebl, wbl, nb);

    layer_build_kernel<<<layer_blocks, 256, 0, stream>>>(
        cur, tmp, Xb1, W1t, bias1, H1, N, rp4g, kendg, eidxg);
    layer_read_kernel<<<layer_blocks, 256, 0, stream>>>(
        rp4g, kendg, eidxg, H1, W2t, bias2, N, batch, gsum);

    cls_kernel<<<(G + 255) / 256, 256, 0, stream>>>(
        gsum, gstart, clas_w, clas_b, gout, G);
}